// Round 1
// baseline (125.358 us; speedup 1.0000x reference)
//
#include <hip/hip_runtime.h>
#include <stdint.h>

typedef unsigned short u16;
typedef float f32x4 __attribute__((ext_vector_type(4)));
typedef __bf16 bf16x8 __attribute__((ext_vector_type(8)));

#define N1 8192
#define N2 8192
#define D 128
#define LD 384   // split-K leading dim: [hi | lo/hi | hi/lo]
#define BM 128
#define BN 128
#define BK 64

__device__ __forceinline__ u16 f32_to_bf16_rne(float f) {
    union { float f; uint32_t u; } v; v.f = f;
    uint32_t u = v.u;
    return (u16)((u + 0x7FFFu + ((u >> 16) & 1u)) >> 16);
}

__device__ __forceinline__ void gload_lds16(const void* g, void* l) {
    __builtin_amdgcn_global_load_lds(
        (const __attribute__((address_space(1))) uint32_t*)g,
        (__attribute__((address_space(3))) uint32_t*)l,
        16, 0, 0);
}

// ---------------- prepass: scale by 1/l, split f32 -> (hi,lo) bf16, row sumsq ----
// S layout per row (LD=384): seg0..2 of 128; lo_seg gets the lo part, others hi.
// A side uses lo_seg=1 ([hi|lo|hi]), B side lo_seg=2 ([hi|hi|lo]) so that
// A'.B'^T = hi.hi + lo.hi + hi.lo.
__global__ void prep_kernel(const float* __restrict__ X, const float* __restrict__ log_l,
                            u16* __restrict__ S, float* __restrict__ nrm,
                            int lo_seg) {
    int t = threadIdx.x;
    int wave = t >> 6, lane = t & 63;
    int row = blockIdx.x * 4 + wave;
    int c0 = lane * 2;
    float2 x = *(const float2*)(X + (size_t)row * D + c0);
    float il0 = __expf(-log_l[c0]);
    float il1 = __expf(-log_l[c0 + 1]);
    float a0 = x.x * il0, a1 = x.y * il1;
    float ss = a0 * a0 + a1 * a1;
    #pragma unroll
    for (int o = 32; o > 0; o >>= 1) ss += __shfl_down(ss, o);
    if (lane == 0) nrm[row] = ss;
    u16 h0 = f32_to_bf16_rne(a0), h1 = f32_to_bf16_rne(a1);
    union { uint32_t u; float f; } hf0, hf1;
    hf0.u = (uint32_t)h0 << 16; hf1.u = (uint32_t)h1 << 16;
    u16 l0 = f32_to_bf16_rne(a0 - hf0.f), l1 = f32_to_bf16_rne(a1 - hf1.f);
    uint32_t hpack = (uint32_t)h0 | ((uint32_t)h1 << 16);
    uint32_t lpack = (uint32_t)l0 | ((uint32_t)l1 << 16);
    u16* base = S + (size_t)row * LD;
    #pragma unroll
    for (int seg = 0; seg < 3; ++seg) {
        uint32_t pk = (seg == lo_seg) ? lpack : hpack;
        *(uint32_t*)(base + seg * D + c0) = pk;
    }
}

// ---------------- main: 128x128-tile bf16 split GEMM (K=384) + fused epilogue ----
__global__ __launch_bounds__(256) void gemm_epi(
    const u16* __restrict__ As, const u16* __restrict__ Bs,
    const float* __restrict__ n1, const float* __restrict__ n2,
    const int* __restrict__ t1, const int* __restrict__ t2,
    const float* __restrict__ log_theta_l, const float* __restrict__ bparam,
    float* __restrict__ C)
{
    __shared__ u16 lA[BM * BK];
    __shared__ u16 lB[BN * BK];
    int t = threadIdx.x;
    int wave = t >> 6, lane = t & 63;
    int wr = wave >> 1, wc = wave & 1;          // 2x2 waves, 64x64 each

    // XCD-aware bijective swizzle (nwg = 4096, divisible by 8)
    int nwg = gridDim.x;
    int wg = blockIdx.x;
    int cpx = nwg >> 3;
    int swz = (wg & 7) * cpx + (wg >> 3);
    int tm = swz >> 6;    // / (N2/BN)
    int tn = swz & 63;

    f32x4 acc[4][4];
    #pragma unroll
    for (int i = 0; i < 4; ++i)
        #pragma unroll
        for (int j = 0; j < 4; ++j) acc[i][j] = (f32x4){0.f, 0.f, 0.f, 0.f};

    const u16* Ag = As + (size_t)(tm * BM) * LD;
    const u16* Bg = Bs + (size_t)(tn * BN) * LD;
    int srow = t >> 3;        // 0..31
    int scol = (t & 7) * 8;   // 0..56

    for (int kt = 0; kt < LD / BK; ++kt) {
        __syncthreads();   // previous compute done before overwrite
        int kc = kt * BK + scol;
        #pragma unroll
        for (int p = 0; p < 4; ++p) {
            gload_lds16(Ag + (size_t)(p * 32 + srow) * LD + kc, (char*)lA + p * 4096 + t * 16);
            gload_lds16(Bg + (size_t)(p * 32 + srow) * LD + kc, (char*)lB + p * 4096 + t * 16);
        }
        __syncthreads();   // drains vmcnt(0) + barrier
        int lr = lane & 15, lg = lane >> 4;
        #pragma unroll
        for (int ks = 0; ks < 2; ++ks) {
            bf16x8 af[4], bfr[4];
            int koff = ks * 32 + lg * 8;
            #pragma unroll
            for (int mi = 0; mi < 4; ++mi)
                af[mi] = *(const bf16x8*)(lA + (wr * 64 + mi * 16 + lr) * BK + koff);
            #pragma unroll
            for (int ni = 0; ni < 4; ++ni)
                bfr[ni] = *(const bf16x8*)(lB + (wc * 64 + ni * 16 + lr) * BK + koff);
            #pragma unroll
            for (int mi = 0; mi < 4; ++mi)
                #pragma unroll
                for (int ni = 0; ni < 4; ++ni)
                    acc[mi][ni] = __builtin_amdgcn_mfma_f32_16x16x32_bf16(
                        af[mi], bfr[ni], acc[mi][ni], 0, 0, 0);
        }
    }

    // ---- epilogue: s = n1 + n2 - 2*dot; K = exp(log_theta - 0.5*s) * mask ----
    float log_theta = log_theta_l[0];
    float bb = bparam[0];
    float lam = fminf(fmaxf(2.f / (1.f + __expf(bb)) - 1.f, 0.f), 1.f);

    int rbase = tm * BM + wr * 64;
    int cbase = tn * BN + wc * 64;
    int lr = lane & 15, lg = lane >> 4;

    float n1r[16]; int t1r[16];
    #pragma unroll
    for (int mi = 0; mi < 4; ++mi)
        #pragma unroll
        for (int r = 0; r < 4; ++r) {
            int row = rbase + mi * 16 + lg * 4 + r;
            n1r[mi * 4 + r] = n1[row];
            t1r[mi * 4 + r] = t1[row];
        }
    float n2c[4]; int t2c[4];
    #pragma unroll
    for (int ni = 0; ni < 4; ++ni) {
        int col = cbase + ni * 16 + lr;
        n2c[ni] = n2[col];
        t2c[ni] = t2[col];
    }
    #pragma unroll
    for (int mi = 0; mi < 4; ++mi)
        #pragma unroll
        for (int ni = 0; ni < 4; ++ni)
            #pragma unroll
            for (int r = 0; r < 4; ++r) {
                int row = rbase + mi * 16 + lg * 4 + r;
                int col = cbase + ni * 16 + lr;
                float dot = acc[mi][ni][r];
                float s = fmaxf(n1r[mi * 4 + r] + n2c[ni] - 2.f * dot, 0.f);
                float k = __expf(fmaf(-0.5f, s, log_theta));
                if (t1r[mi * 4 + r] != t2c[ni]) k *= lam;
                C[(size_t)row * N2 + col] = k;
            }
}

// ---------------- fallback (only if ws too small): direct f32, exact diff form ----
__global__ void fallback_kernel(const float* __restrict__ X1v, const float* __restrict__ X2v,
                                const float* __restrict__ log_l,
                                const float* __restrict__ log_theta_l, const float* __restrict__ bp,
                                const int* __restrict__ t1, const int* __restrict__ t2,
                                float* __restrict__ C)
{
    __shared__ float sA[16][128];
    __shared__ float sB[16][128];
    __shared__ float sil[128];
    int tx = threadIdx.x, ty = threadIdx.y;
    int tid = ty * 16 + tx;
    int row0 = blockIdx.y * 16, col0 = blockIdx.x * 16;
    if (tid < 128) sil[tid] = __expf(-log_l[tid]);
    __syncthreads();
    for (int i = tid; i < 16 * 128; i += 256) {
        int r = i >> 7, c = i & 127;
        sA[r][c] = X1v[(size_t)(row0 + r) * D + c] * sil[c];
        sB[r][c] = X2v[(size_t)(col0 + r) * D + c] * sil[c];
    }
    __syncthreads();
    float s = 0.f;
    for (int k = 0; k < D; ++k) {
        float d = sA[ty][k] - sB[tx][k];
        s = fmaf(d, d, s);
    }
    float log_theta = log_theta_l[0];
    float bb = bp[0];
    float lam = fminf(fmaxf(2.f / (1.f + __expf(bb)) - 1.f, 0.f), 1.f);
    int row = row0 + ty, col = col0 + tx;
    float k = __expf(fmaf(-0.5f, fmaxf(s, 0.f), log_theta));
    if (t1[row] != t2[col]) k *= lam;
    C[(size_t)row * N2 + col] = k;
}

extern "C" void kernel_launch(void* const* d_in, const int* in_sizes, int n_in,
                              void* d_out, int out_size, void* d_ws, size_t ws_size,
                              hipStream_t stream)
{
    const float* X1 = (const float*)d_in[0];
    const float* X2 = (const float*)d_in[1];
    const float* log_l = (const float*)d_in[2];
    const float* log_theta = (const float*)d_in[3];
    const float* bp = (const float*)d_in[4];
    const int* t1 = (const int*)d_in[5];
    const int* t2 = (const int*)d_in[6];
    float* C = (float*)d_out;

    size_t szA = (size_t)N1 * LD * sizeof(u16);
    size_t szB = (size_t)N2 * LD * sizeof(u16);
    size_t need = szA + szB + (size_t)(N1 + N2) * sizeof(float);

    if (ws_size >= need) {
        u16* As = (u16*)d_ws;
        u16* Bs = (u16*)((char*)d_ws + szA);
        float* nrm1 = (float*)((char*)d_ws + szA + szB);
        float* nrm2 = nrm1 + N1;
        prep_kernel<<<N1 / 4, 256, 0, stream>>>(X1, log_l, As, nrm1, 1);
        prep_kernel<<<N2 / 4, 256, 0, stream>>>(X2, log_l, Bs, nrm2, 2);
        gemm_epi<<<(N1 / BM) * (N2 / BN), 256, 0, stream>>>(As, Bs, nrm1, nrm2,
                                                            t1, t2, log_theta, bp, C);
    } else {
        dim3 blk(16, 16), grd(N2 / 16, N1 / 16);
        fallback_kernel<<<grd, blk, 0, stream>>>(X1, X2, log_l, log_theta, bp, t1, t2, C);
    }
}